// Round 7
// baseline (485.999 us; speedup 1.0000x reference)
//
#include <hip/hip_runtime.h>
#include <hip/hip_bf16.h>

#define IN_FEATS 602
#define KP2 608              // K padded to 19*32
#define N_HIDDEN 256
#define N_CLASSES 41
#define N_SRC0 292864
#define N_DST0 11264
#define N_DST1 1024
#define FAN0 25
#define FAN1 10
#define NBN (N_SRC0 / 32)    // 9152 neigh-gemm blocks
#define NBS (N_DST0 / 32)    // 352 self-gemm blocks

typedef __attribute__((ext_vector_type(2))) float f32x2;
typedef __attribute__((ext_vector_type(4))) float f32x4;
typedef __attribute__((ext_vector_type(8))) short bf16x8;

// round-to-nearest-even f32 -> bf16, packed pair
static __device__ __forceinline__ unsigned pack_bf16x2(float lo, float hi) {
    unsigned a = __float_as_uint(lo);
    unsigned b = __float_as_uint(hi);
    a = (a + 0x7fffu + ((a >> 16) & 1u)) >> 16;
    b = (b + 0x7fffu + ((b >> 16) & 1u)) >> 16;
    return (a & 0xffffu) | (b << 16);
}

// ---------------------------------------------------------------------------
// wprep: W[602][256] f32 -> Wt[256][608] bf16 (transposed, K-major, zero-pad).
// (verified R6)
// ---------------------------------------------------------------------------
__global__ __launch_bounds__(256) void wprep_kernel(
    const float* __restrict__ Ws, const float* __restrict__ Wn,
    __hip_bfloat16* __restrict__ Wst, __hip_bfloat16* __restrict__ Wnt)
{
    const float* W = blockIdx.z ? Wn : Ws;
    __hip_bfloat16* Wt = blockIdx.z ? Wnt : Wst;

    __shared__ float tile[32][33];
    const int k0 = blockIdx.x * 32, n0 = blockIdx.y * 32;
    const int tx = threadIdx.x & 31, ty = threadIdx.x >> 5;   // 32 x 8

    #pragma unroll
    for (int i = 0; i < 4; ++i) {
        const int k = k0 + ty + i * 8;
        const int n = n0 + tx;
        tile[ty + i * 8][tx] = (k < IN_FEATS) ? W[(size_t)k * N_HIDDEN + n] : 0.f;
    }
    __syncthreads();
    #pragma unroll
    for (int i = 0; i < 4; ++i) {
        const int n = n0 + ty + i * 8;
        const int k = k0 + tx;
        Wt[(size_t)n * KP2 + k] = __float2bfloat16(tile[tx][ty + i * 8]);
    }
}

// ---------------------------------------------------------------------------
// zgemm: z[m][:] = bf16( x[m] @ W ).  Block = 32 rows x 256 cols, FULL K in LDS.
// Stage: contiguous 512-B wave reads of x (nontemporal -> keep L3 for zn),
// f32->bf16 pack, XOR-swizzled LDS (stride 80 x 16-B chunks, chunk ^= row&7).
// Compute: no further barriers; 4 waves x (32 rows x 64 cols); B streamed
// from L2-resident Wt with 2-deep register prefetch (R4-verified pattern).
// ---------------------------------------------------------------------------
__global__ __launch_bounds__(256, 4) void zgemm_kernel(
    const float* __restrict__ x,
    const __hip_bfloat16* __restrict__ Wnt,   // [256][608]
    const __hip_bfloat16* __restrict__ Wst,   // [256][608]
    __hip_bfloat16* __restrict__ zn,          // [292864][256]
    __hip_bfloat16* __restrict__ zs)          // [11264][256]
{
    __shared__ __align__(16) char smA[32 * 1280];   // 40 KB

    const int bb = blockIdx.x;
    const bool self = (bb >= NBN);
    const __hip_bfloat16* Wt = self ? Wst : Wnt;
    __hip_bfloat16* zout      = self ? zs  : zn;
    const int m0 = (self ? bb - NBN : bb) * 32;

    const int tid  = threadIdx.x;
    const int lane = tid & 63;
    const int w    = tid >> 6;          // wave 0..3
    const int r    = lane & 15;
    const int g    = lane >> 4;

    // ---- stage: wave w loads rows w*8 .. w*8+7 (contiguous 512-B segments) ----
    #pragma unroll
    for (int j = 0; j < 8; ++j) {
        const int row = w * 8 + j;
        const float* xr = x + (size_t)(m0 + row) * IN_FEATS;
        #pragma unroll
        for (int c = 0; c < 5; ++c) {
            const int k = lane * 2 + c * 128;
            f32x2 v = {0.f, 0.f};
            if (k < IN_FEATS) v = __builtin_nontemporal_load((const f32x2*)(xr + k));
            const int chunk = (lane >> 2) + c * 16;      // 16-B chunk index, 0..79
            *(unsigned*)(smA + row * 1280 + ((chunk ^ (row & 7)) << 4) + ((lane & 3) << 2))
                = pack_bf16x2(v[0], v[1]);
        }
    }
    __syncthreads();

    // ---- compute: wave w -> cols [w*64, w*64+64), all 32 rows ----
    f32x4 acc[2][4] = {};
    const __hip_bfloat16* Bp = Wt + (size_t)(w * 64 + r) * KP2 + g * 8;

#define LOADB(T, B) { _Pragma("unroll") \
    for (int nf = 0; nf < 4; ++nf) \
        B[nf] = *(const bf16x8*)(Bp + (size_t)nf * 16 * KP2 + (T) * 32); }
#define DOMFMA(T, B) { _Pragma("unroll") \
    for (int mf = 0; mf < 2; ++mf) { \
        const bf16x8 af = *(const bf16x8*)(smA + (mf * 16 + r) * 1280 + \
                              ((((T) * 4 + g) ^ (r & 7)) << 4)); \
        _Pragma("unroll") \
        for (int nf = 0; nf < 4; ++nf) \
            acc[mf][nf] = __builtin_amdgcn_mfma_f32_16x16x32_bf16(af, B[nf], acc[mf][nf], 0, 0, 0); } }

    bf16x8 bA[4], bB[4];
    LOADB(0, bA)
    for (int t = 0; t < 18; t += 2) {      // 19 K-steps, 2-deep B prefetch
        LOADB(t + 1, bB)
        DOMFMA(t, bA)
        LOADB(t + 2, bA)
        DOMFMA(t + 1, bB)
    }
    DOMFMA(18, bA)
#undef LOADB
#undef DOMFMA

    // epilogue: col = w*64 + nf*16 + r, row = m0 + mf*16 + g*4 + j (m89 layout)
    #pragma unroll
    for (int mf = 0; mf < 2; ++mf)
        #pragma unroll
        for (int nf = 0; nf < 4; ++nf) {
            const int col = w * 64 + nf * 16 + r;
            #pragma unroll
            for (int j = 0; j < 4; ++j) {
                const int row = m0 + mf * 16 + g * 4 + j;
                zout[(size_t)row * N_HIDDEN + col] = __float2bfloat16(acc[mf][nf][j]);
            }
        }
}

// ---------------------------------------------------------------------------
// zfin: h[d] = relu( zs[d] + mean_25 zn[idx0[d]] + b0 )   (f32 out; verified R6)
// ---------------------------------------------------------------------------
__global__ __launch_bounds__(256) void zfin_kernel(
    const __hip_bfloat16* __restrict__ zn,
    const __hip_bfloat16* __restrict__ zs,
    const int* __restrict__ idx0,
    const float* __restrict__ b0,
    float* __restrict__ h)
{
    const int w = threadIdx.x >> 6;
    const int lane = threadIdx.x & 63;
    const int d = blockIdx.x * 4 + w;

    __shared__ int sidx[4][FAN0];
    if (lane < FAN0) sidx[w][lane] = idx0[d * FAN0 + lane];
    __syncthreads();

    float s0 = 0.f, s1 = 0.f, s2 = 0.f, s3 = 0.f;
    #pragma unroll
    for (int n = 0; n < FAN0; ++n) {
        const uint2 v = *(const uint2*)&zn[(size_t)sidx[w][n] * N_HIDDEN + lane * 4];
        s0 += __uint_as_float(v.x << 16);
        s1 += __uint_as_float(v.x & 0xffff0000u);
        s2 += __uint_as_float(v.y << 16);
        s3 += __uint_as_float(v.y & 0xffff0000u);
    }
    const uint2 sv = *(const uint2*)&zs[(size_t)d * N_HIDDEN + lane * 4];
    const float4 bv = *(const float4*)&b0[lane * 4];

    float4 o;
    o.x = fmaxf(__uint_as_float(sv.x << 16)          + s0 * (1.0f / FAN0) + bv.x, 0.f);
    o.y = fmaxf(__uint_as_float(sv.x & 0xffff0000u)  + s1 * (1.0f / FAN0) + bv.y, 0.f);
    o.z = fmaxf(__uint_as_float(sv.y << 16)          + s2 * (1.0f / FAN0) + bv.z, 0.f);
    o.w = fmaxf(__uint_as_float(sv.y & 0xffff0000u)  + s3 * (1.0f / FAN0) + bv.w, 0.f);
    *(float4*)&h[(size_t)d * N_HIDDEN + lane * 4] = o;
}

// ---------------------------------------------------------------------------
// tail: out[d] = h[d]@Ws1 + (mean_10 h[idx1])@Wn1 + b1.  (verified R5/R6)
// ---------------------------------------------------------------------------
__global__ __launch_bounds__(256) void tail_kernel(
    const float* __restrict__ h,
    const int* __restrict__ idx1,
    const float* __restrict__ Ws,     // [256][41]
    const float* __restrict__ Wn,     // [256][41]
    const float* __restrict__ b,      // [41]
    float* __restrict__ out)          // [1024][41]
{
    const int w = threadIdx.x >> 6;
    const int lane = threadIdx.x & 63;
    const int d = blockIdx.x * 4 + w;

    __shared__ float hd[4][N_HIDDEN];
    __shared__ float hn[4][N_HIDDEN];
    __shared__ int sidx[4][FAN1];
    if (lane < FAN1) sidx[w][lane] = idx1[d * FAN1 + lane];
    __syncthreads();

    {
        const int k0 = lane * 4;
        const float4 self = *(const float4*)&h[(size_t)d * N_HIDDEN + k0];
        float ax = 0.f, ay = 0.f, az = 0.f, aw = 0.f;
        #pragma unroll
        for (int i = 0; i < FAN1; ++i) {
            const float4 v = *(const float4*)&h[(size_t)sidx[w][i] * N_HIDDEN + k0];
            ax += v.x; ay += v.y; az += v.z; aw += v.w;
        }
        *(float4*)&hd[w][k0] = self;
        hn[w][k0 + 0] = ax * (1.0f / FAN1);
        hn[w][k0 + 1] = ay * (1.0f / FAN1);
        hn[w][k0 + 2] = az * (1.0f / FAN1);
        hn[w][k0 + 3] = aw * (1.0f / FAN1);
    }
    __syncthreads();

    if (lane < N_CLASSES) {
        const int n = lane;
        float a0 = b[n], a1 = 0.f, a2 = 0.f, a3 = 0.f;
        #pragma unroll 4
        for (int k = 0; k < N_HIDDEN; k += 4) {
            a0 += hd[w][k + 0] * Ws[(k + 0) * N_CLASSES + n] + hn[w][k + 0] * Wn[(k + 0) * N_CLASSES + n];
            a1 += hd[w][k + 1] * Ws[(k + 1) * N_CLASSES + n] + hn[w][k + 1] * Wn[(k + 1) * N_CLASSES + n];
            a2 += hd[w][k + 2] * Ws[(k + 2) * N_CLASSES + n] + hn[w][k + 2] * Wn[(k + 2) * N_CLASSES + n];
            a3 += hd[w][k + 3] * Ws[(k + 3) * N_CLASSES + n] + hn[w][k + 3] * Wn[(k + 3) * N_CLASSES + n];
        }
        out[(size_t)d * N_CLASSES + n] = a0 + a1 + a2 + a3;
    }
}

// ---------------------------------------------------------------------------
extern "C" void kernel_launch(void* const* d_in, const int* in_sizes, int n_in,
                              void* d_out, int out_size, void* d_ws, size_t ws_size,
                              hipStream_t stream) {
    const float* x       = (const float*)d_in[0];
    const float* Wself0  = (const float*)d_in[1];
    const float* Wneigh0 = (const float*)d_in[2];
    const float* b0      = (const float*)d_in[3];
    const float* Wself1  = (const float*)d_in[4];
    const float* Wneigh1 = (const float*)d_in[5];
    const float* b1      = (const float*)d_in[6];
    const int*   idx0    = (const int*)d_in[7];
    const int*   idx1    = (const int*)d_in[8];
    float* out = (float*)d_out;

    // ws: zn bf16 [292864*256] (150MB) | zs bf16 [11264*256] | h f32 [11264*256]
    //     | Wst bf16 [256*608] | Wnt bf16 [256*608]
    __hip_bfloat16* zn  = (__hip_bfloat16*)d_ws;
    __hip_bfloat16* zs  = zn + (size_t)N_SRC0 * N_HIDDEN;
    float*          h   = (float*)(zs + (size_t)N_DST0 * N_HIDDEN);
    __hip_bfloat16* Wst = (__hip_bfloat16*)(h + (size_t)N_DST0 * N_HIDDEN);
    __hip_bfloat16* Wnt = Wst + (size_t)N_HIDDEN * KP2;

    wprep_kernel<<<dim3(KP2 / 32, N_HIDDEN / 32, 2), 256, 0, stream>>>(Wself0, Wneigh0, Wst, Wnt);
    zgemm_kernel<<<NBN + NBS, 256, 0, stream>>>(x, Wnt, Wst, zn, zs);
    zfin_kernel<<<N_DST0 / 4, 256, 0, stream>>>(zn, zs, idx0, b0, h);
    tail_kernel<<<N_DST1 / 4, 256, 0, stream>>>(h, idx1, Wself1, Wneigh1, b1, out);
}

// Round 8
// 232.237 us; speedup vs baseline: 2.0927x; 2.0927x over previous
//
#include <hip/hip_runtime.h>
#include <hip/hip_bf16.h>

#define IN_FEATS 602
#define N_HIDDEN 256
#define N_CLASSES 41
#define N_SRC0 292864
#define N_DST0 11264
#define N_DST1 1024
#define FAN0 25
#define FAN1 10
#define KPAD 1216            // 1204 rounded up to multiple of 64

typedef __attribute__((ext_vector_type(4))) float f32x4;
typedef __attribute__((ext_vector_type(8))) short bf16x8;   // 8 bf16 = 4 VGPRs

// round-to-nearest-even f32 -> bf16, packed pair
static __device__ __forceinline__ unsigned pack_bf16x2(float lo, float hi) {
    unsigned a = __float_as_uint(lo);
    unsigned b = __float_as_uint(hi);
    a = (a + 0x7fffu + ((a >> 16) & 1u)) >> 16;
    b = (b + 0x7fffu + ((b >> 16) & 1u)) >> 16;
    return (a & 0xffffu) | (b << 16);
}

// ---------------------------------------------------------------------------
// Kernel 1: build A[d] = [ bf16(x[d]) (602) | bf16(mean_25 x[idx]) (602) | 0 pad ]
// One wave per dst (4 dsts/block). ROW-CONTIGUOUS neighbor reads: all 5
// 512-B chunks of a neighbor row issue back-to-back (one DRAM page activation
// per row instead of 5). acc[5] per-chunk accumulators; unroll-5 on n keeps
// 25 chunk-loads in flight.
// ---------------------------------------------------------------------------
__global__ __launch_bounds__(256) void agg0_kernel(
    const float* __restrict__ x,
    const int* __restrict__ idx,
    __hip_bfloat16* __restrict__ A)
{
    const int wave = threadIdx.x >> 6;
    const int lane = threadIdx.x & 63;
    const int d = blockIdx.x * 4 + wave;

    __shared__ int sidx[4][FAN0];
    if (lane < FAN0) sidx[wave][lane] = idx[d * FAN0 + lane];
    __syncthreads();

    unsigned* Arow = (unsigned*)(A + (size_t)d * KPAD);
    const float* xself = x + (size_t)d * IN_FEATS;

    // zero pad cols 1204..1215 (uint slots 602..607)
    if (lane < 6) Arow[602 + lane] = 0u;

    float accx[5], accy[5];
    #pragma unroll
    for (int c = 0; c < 5; ++c) { accx[c] = 0.f; accy[c] = 0.f; }

    #pragma unroll 5
    for (int n = 0; n < FAN0; ++n) {
        const float* xr = x + (size_t)sidx[wave][n] * IN_FEATS;
        #pragma unroll
        for (int c = 0; c < 5; ++c) {
            const int f = c * 128 + lane * 2;
            if (f < IN_FEATS) {
                const float2 v = *(const float2*)&xr[f];
                accx[c] += v.x; accy[c] += v.y;
            }
        }
    }

    #pragma unroll
    for (int c = 0; c < 5; ++c) {
        const int f = c * 128 + lane * 2;
        if (f < IN_FEATS) {
            const int f2 = f >> 1;
            const float2 sv = *(const float2*)&xself[f];
            Arow[f2] = pack_bf16x2(sv.x, sv.y);
            // neigh half starts at element 602 -> byte 1204 (4-B aligned)
            *(unsigned*)((char*)Arow + 1204 + f2 * 4) =
                pack_bf16x2(accx[c] * (1.0f / FAN0), accy[c] * (1.0f / FAN0));
        }
    }
}

// ---------------------------------------------------------------------------
// Kernel 2: Wt[n][k] = bf16( k<602 ? Wself0[k][n] : k<1204 ? Wneigh0[k-602][n] : 0 )
// Wt is [N_HIDDEN][KPAD] bf16. (verified R2)
// ---------------------------------------------------------------------------
__global__ __launch_bounds__(256) void wprep_kernel(
    const float* __restrict__ Ws,
    const float* __restrict__ Wn,
    __hip_bfloat16* __restrict__ Wt)
{
    __shared__ float tile[32][33];
    const int k0 = blockIdx.x * 32, n0 = blockIdx.y * 32;
    const int tx = threadIdx.x & 31, ty = threadIdx.x >> 5;   // 32 x 8

    #pragma unroll
    for (int i = 0; i < 4; ++i) {
        const int k = k0 + ty + i * 8;
        const int n = n0 + tx;
        float v = 0.f;
        if (k < IN_FEATS)            v = Ws[(size_t)k * N_HIDDEN + n];
        else if (k < 2 * IN_FEATS)   v = Wn[(size_t)(k - IN_FEATS) * N_HIDDEN + n];
        tile[ty + i * 8][tx] = v;
    }
    __syncthreads();
    #pragma unroll
    for (int i = 0; i < 4; ++i) {
        const int n = n0 + ty + i * 8;
        const int k = k0 + tx;
        Wt[(size_t)n * KPAD + k] = __float2bfloat16(tile[tx][ty + i * 8]);
    }
}

// ---------------------------------------------------------------------------
// Kernel 3: h = relu(A @ Wt^T + b0) via bf16 MFMA. (verified R2: 64x64, BK=64)
// ---------------------------------------------------------------------------
#define BKK 64
#define LDSW 72

__global__ __launch_bounds__(256) void gemm0_mfma(
    const __hip_bfloat16* __restrict__ A,     // [N_DST0][KPAD]
    const __hip_bfloat16* __restrict__ Wt,    // [N_HIDDEN][KPAD]
    const float* __restrict__ bias,           // [256]
    float* __restrict__ h)                    // [N_DST0][256]
{
    __shared__ __hip_bfloat16 As[64 * LDSW];
    __shared__ __hip_bfloat16 Bs[64 * LDSW];

    const int tid  = threadIdx.x;
    const int lane = tid & 63;
    const int wave = tid >> 6;
    const int wm = wave >> 1, wn = wave & 1;    // 2x2 waves of 32x32
    const int g = lane >> 4, r = lane & 15;
    const int m0 = blockIdx.y * 64, n0 = blockIdx.x * 64;

    const int srow = tid >> 2;
    const int sc   = (tid & 3) * 16;

    const size_t a_off = (size_t)(m0 + srow) * KPAD + sc;
    const size_t b_off = (size_t)(n0 + srow) * KPAD + sc;

    f32x4 acc[2][2] = {};

    for (int k0 = 0; k0 < KPAD; k0 += BKK) {
        *(float4*)&As[srow * LDSW + sc]     = *(const float4*)&A[a_off + k0];
        *(float4*)&As[srow * LDSW + sc + 8] = *(const float4*)&A[a_off + k0 + 8];
        *(float4*)&Bs[srow * LDSW + sc]     = *(const float4*)&Wt[b_off + k0];
        *(float4*)&Bs[srow * LDSW + sc + 8] = *(const float4*)&Wt[b_off + k0 + 8];
        __syncthreads();

        #pragma unroll
        for (int kh = 0; kh < 2; ++kh) {
            const bf16x8 af0 = *(const bf16x8*)&As[(wm * 32 +      r) * LDSW + kh * 32 + g * 8];
            const bf16x8 af1 = *(const bf16x8*)&As[(wm * 32 + 16 + r) * LDSW + kh * 32 + g * 8];
            const bf16x8 bf0 = *(const bf16x8*)&Bs[(wn * 32 +      r) * LDSW + kh * 32 + g * 8];
            const bf16x8 bf1 = *(const bf16x8*)&Bs[(wn * 32 + 16 + r) * LDSW + kh * 32 + g * 8];

            acc[0][0] = __builtin_amdgcn_mfma_f32_16x16x32_bf16(af0, bf0, acc[0][0], 0, 0, 0);
            acc[0][1] = __builtin_amdgcn_mfma_f32_16x16x32_bf16(af0, bf1, acc[0][1], 0, 0, 0);
            acc[1][0] = __builtin_amdgcn_mfma_f32_16x16x32_bf16(af1, bf0, acc[1][0], 0, 0, 0);
            acc[1][1] = __builtin_amdgcn_mfma_f32_16x16x32_bf16(af1, bf1, acc[1][1], 0, 0, 0);
        }
        __syncthreads();
    }

    // C/D layout (m89-verified): col = lane&15, row = (lane>>4)*4 + j
    #pragma unroll
    for (int mh = 0; mh < 2; ++mh)
        #pragma unroll
        for (int nh = 0; nh < 2; ++nh) {
            const int col = n0 + wn * 32 + nh * 16 + r;
            const float bv = bias[col];
            #pragma unroll
            for (int j = 0; j < 4; ++j) {
                const int row = m0 + wm * 32 + mh * 16 + g * 4 + j;
                const float v = acc[mh][nh][j] + bv;
                h[(size_t)row * N_HIDDEN + col] = fmaxf(v, 0.f);
            }
        }
}

// ---------------------------------------------------------------------------
// Kernel 4: out[d] = h[d]@Ws1 + (mean_10 h[idx1])@Wn1 + b1.  4 dsts/block.
// (verified R5)
// ---------------------------------------------------------------------------
__global__ __launch_bounds__(256) void tail_kernel(
    const float* __restrict__ h,
    const int* __restrict__ idx1,
    const float* __restrict__ Ws,     // [256][41]
    const float* __restrict__ Wn,     // [256][41]
    const float* __restrict__ b,      // [41]
    float* __restrict__ out)          // [1024][41]
{
    const int w = threadIdx.x >> 6;
    const int lane = threadIdx.x & 63;
    const int d = blockIdx.x * 4 + w;

    __shared__ float hd[4][N_HIDDEN];
    __shared__ float hn[4][N_HIDDEN];
    __shared__ int sidx[4][FAN1];
    if (lane < FAN1) sidx[w][lane] = idx1[d * FAN1 + lane];
    __syncthreads();

    {
        const int k0 = lane * 4;
        const float4 self = *(const float4*)&h[(size_t)d * N_HIDDEN + k0];
        float ax = 0.f, ay = 0.f, az = 0.f, aw = 0.f;
        #pragma unroll
        for (int i = 0; i < FAN1; ++i) {
            const float4 v = *(const float4*)&h[(size_t)sidx[w][i] * N_HIDDEN + k0];
            ax += v.x; ay += v.y; az += v.z; aw += v.w;
        }
        *(float4*)&hd[w][k0] = self;
        hn[w][k0 + 0] = ax * (1.0f / FAN1);
        hn[w][k0 + 1] = ay * (1.0f / FAN1);
        hn[w][k0 + 2] = az * (1.0f / FAN1);
        hn[w][k0 + 3] = aw * (1.0f / FAN1);
    }
    __syncthreads();

    if (lane < N_CLASSES) {
        const int n = lane;
        float a0 = b[n], a1 = 0.f, a2 = 0.f, a3 = 0.f;
        #pragma unroll 4
        for (int k = 0; k < N_HIDDEN; k += 4) {
            a0 += hd[w][k + 0] * Ws[(k + 0) * N_CLASSES + n] + hn[w][k + 0] * Wn[(k + 0) * N_CLASSES + n];
            a1 += hd[w][k + 1] * Ws[(k + 1) * N_CLASSES + n] + hn[w][k + 1] * Wn[(k + 1) * N_CLASSES + n];
            a2 += hd[w][k + 2] * Ws[(k + 2) * N_CLASSES + n] + hn[w][k + 2] * Wn[(k + 2) * N_CLASSES + n];
            a3 += hd[w][k + 3] * Ws[(k + 3) * N_CLASSES + n] + hn[w][k + 3] * Wn[(k + 3) * N_CLASSES + n];
        }
        out[(size_t)d * N_CLASSES + n] = a0 + a1 + a2 + a3;
    }
}

// ---------------------------------------------------------------------------
extern "C" void kernel_launch(void* const* d_in, const int* in_sizes, int n_in,
                              void* d_out, int out_size, void* d_ws, size_t ws_size,
                              hipStream_t stream) {
    const float* x       = (const float*)d_in[0];
    const float* Wself0  = (const float*)d_in[1];
    const float* Wneigh0 = (const float*)d_in[2];
    const float* b0      = (const float*)d_in[3];
    const float* Wself1  = (const float*)d_in[4];
    const float* Wneigh1 = (const float*)d_in[5];
    const float* b1      = (const float*)d_in[6];
    const int*   idx0    = (const int*)d_in[7];
    const int*   idx1    = (const int*)d_in[8];
    float* out = (float*)d_out;

    // ws layout: A bf16 [11264*1216] | Wt bf16 [256*1216] | h f32 [11264*256]
    __hip_bfloat16* Abf = (__hip_bfloat16*)d_ws;
    __hip_bfloat16* Wt  = Abf + (size_t)N_DST0 * KPAD;
    float*          h   = (float*)(Wt + (size_t)N_HIDDEN * KPAD);

    wprep_kernel<<<dim3(KPAD / 32, N_HIDDEN / 32), 256, 0, stream>>>(Wself0, Wneigh0, Wt);
    agg0_kernel<<<N_DST0 / 4, 256, 0, stream>>>(x, idx0, Abf);
    gemm0_mfma<<<dim3(N_HIDDEN / 64, N_DST0 / 64), 256, 0, stream>>>(Abf, Wt, b0, h);
    tail_kernel<<<N_DST1 / 4, 256, 0, stream>>>(h, idx1, Wself1, Wneigh1, b1, out);
}